// Round 9
// baseline (60.394 us; speedup 1.0000x reference)
//
#include <hip/hip_runtime.h>

#define B_N    1024
#define F_DIMC 768
#define M_DIM  512
#define C_N    100
#define KHALF  (F_DIMC / 2)     // 384 per K-split half
#define NT2    (KHALF / 32)     // 12 k-steps of BK=32
#define NGEMM  512              // 256 tiles x 2 K-halves
#define NIDX   25               // 25 blocks x 4 waves = 100 classes

// ---------------------------------------------------------------------------
// Kernel 1: partial GEMM (K-split x2) summed into part via fp32 atomics
// (2 addends per element -> order-independent, bit-deterministic), no relu.
// blocks 0..511: 32x64 tile, half-K each, 256 thr, double-buffered LDS.
// blocks 512..536: one wave per class, ballot-based stable rank index build.
// ---------------------------------------------------------------------------
__global__ __launch_bounds__(256) void gemm_index_kernel(
    const float* __restrict__ X, const float* __restrict__ W,
    const int* __restrict__ labels, float* __restrict__ part,
    int* __restrict__ counts, int* __restrict__ idx) {
  __shared__ float As[2][32][36];  // k-major A tile
  __shared__ float Bs[2][32][64];
  __shared__ int   lab[B_N];

  const int t = threadIdx.x;

  if (blockIdx.x >= NGEMM) {  // ---- index path ----
    for (int i = t; i < B_N; i += 256) lab[i] = labels[i];
    __syncthreads();
    const int w    = t >> 6;
    const int lane = t & 63;
    const int c    = ((int)blockIdx.x - NGEMM) * 4 + w;
    if (c < C_N) {
      int base = 0;
      for (int ch = 0; ch < 16; ++ch) {
        const int j = ch * 64 + lane;
        const bool hit = (lab[j] == c);
        const unsigned long long mask = __ballot(hit);
        if (hit) {
          const int r = __popcll(mask & ((1ull << lane) - 1ull));
          idx[c * B_N + base + r] = j;
        }
        base += __popcll(mask);
      }
      if (lane == 0) counts[c] = base;
    }
    return;
  }

  // ---- GEMM path ----
  const int kb   = (int)blockIdx.x >> 8;        // K-half 0/1
  const int tile = (int)blockIdx.x & 255;
  const int bm = (tile >> 3) * 32;
  const int bn = (tile & 7) * 64;
  const int tx = t & 15;   // col group (x4) -> 64 cols
  const int ty = t >> 4;   // row group (x2) -> 32 rows

  const int ar  = t >> 3;        // A row 0..31
  const int akq = (t & 7) * 4;   // A k-quad
  const int bk0 = t >> 4;        // B k-rows
  const int bk1 = bk0 + 16;
  const int bnq = (t & 15) * 4;  // B col-quad

  const float* __restrict__ Arow =
      X + (size_t)(bm + ar) * F_DIMC + kb * KHALF + akq;
  const float* __restrict__ Bcol =
      W + (size_t)kb * KHALF * M_DIM + bn + bnq;

  float4 pa  = *(const float4*)(Arow);
  float4 pb0 = *(const float4*)(Bcol + (size_t)bk0 * M_DIM);
  float4 pb1 = *(const float4*)(Bcol + (size_t)bk1 * M_DIM);

  float acc[2][4] = {};

  As[0][akq + 0][ar] = pa.x;
  As[0][akq + 1][ar] = pa.y;
  As[0][akq + 2][ar] = pa.z;
  As[0][akq + 3][ar] = pa.w;
  *(float4*)&Bs[0][bk0][bnq] = pb0;
  *(float4*)&Bs[0][bk1][bnq] = pb1;
  __syncthreads();

  for (int it = 0; it < NT2; ++it) {
    const int cur = it & 1;
    if (it + 1 < NT2) {
      const int k0 = (it + 1) * 32;
      pa  = *(const float4*)(Arow + k0);
      pb0 = *(const float4*)(Bcol + (size_t)(k0 + bk0) * M_DIM);
      pb1 = *(const float4*)(Bcol + (size_t)(k0 + bk1) * M_DIM);
    }
#pragma unroll
    for (int kk = 0; kk < 32; ++kk) {
      float2 av = *(const float2*)&As[cur][kk][ty * 2];
      float4 bv = *(const float4*)&Bs[cur][kk][tx * 4];
      acc[0][0] += av.x * bv.x;
      acc[0][1] += av.x * bv.y;
      acc[0][2] += av.x * bv.z;
      acc[0][3] += av.x * bv.w;
      acc[1][0] += av.y * bv.x;
      acc[1][1] += av.y * bv.y;
      acc[1][2] += av.y * bv.z;
      acc[1][3] += av.y * bv.w;
    }
    if (it + 1 < NT2) {
      const int nxt = cur ^ 1;
      As[nxt][akq + 0][ar] = pa.x;
      As[nxt][akq + 1][ar] = pa.y;
      As[nxt][akq + 2][ar] = pa.z;
      As[nxt][akq + 3][ar] = pa.w;
      *(float4*)&Bs[nxt][bk0][bnq] = pb0;
      *(float4*)&Bs[nxt][bk1][bnq] = pb1;
    }
    __syncthreads();
  }

#pragma unroll
  for (int j = 0; j < 2; ++j) {
    float* __restrict__ d = part + (size_t)(bm + ty * 2 + j) * M_DIM + bn + tx * 4;
    unsafeAtomicAdd(d + 0, acc[j][0]);
    unsafeAtomicAdd(d + 1, acc[j][1]);
    unsafeAtomicAdd(d + 2, acc[j][2]);
    unsafeAtomicAdd(d + 3, acc[j][3]);
  }
}

// ---------------------------------------------------------------------------
// Kernel 2: phi quad-panels + mu/count. feat = relu(part) built in staging.
// grid = (5, C) x 1024 thr. x<4: 4 panels of 32 rows x 512 cols per block;
// one 16x512 LDS stage serves all 4 panels (4x less staging than R8).
// x==4: mu/count (512 active threads).
// Thread: tp=t>>8 panel, tr=(t>>6)&3 row-group (x8 rows), tc=t&63 cols
// {tc*4, 256+tc*4}. av = 2x b128 wave-uniform, bv = 2x b128 lane-contiguous.
// Stores: normal (L2-routed) float4, 1KB dense per wave-instr.
// ---------------------------------------------------------------------------
__global__ __launch_bounds__(1024, 1) void phi_mu_kernel(
    const float* __restrict__ part, const int* __restrict__ counts,
    const int* __restrict__ idx, float* __restrict__ phi,
    float* __restrict__ mu, float* __restrict__ cnt_out) {
  const int c = blockIdx.y;
  const int n = counts[c];
  const int* __restrict__ id = idx + c * B_N;
  const int t = threadIdx.x;

  if (blockIdx.x == 4) {  // ---- mu / count path ----
    if (t < M_DIM) {
      float a = 0.f;
      for (int s = 0; s < n; ++s)
        a += fmaxf(part[(size_t)id[s] * M_DIM + t], 0.f);
      mu[(size_t)c * M_DIM + t] = a;
    }
    if (t == 0) cnt_out[c] = (float)n;
    return;
  }

  // ---- phi quad-panel path ----
  const int tp = t >> 8;        // panel-in-block 0..3
  const int tr = (t >> 6) & 3;  // row group (x8 rows)
  const int tc = t & 63;        // col group: cols tc*4 and 256+tc*4
  const int prow = ((int)blockIdx.x * 4 + tp) * 32 + tr * 8;  // 8 rows from here

  __shared__ float F[16][M_DIM];

  float acc[8][8] = {};  // [r][q]: q<4 -> col tc*4+q ; q>=4 -> 256+tc*4+q-4

  for (int s0 = 0; s0 < n; s0 += 16) {
    const int chunk = min(16, n - s0);
    if (s0) __syncthreads();           // protect F before overwrite
    const int nslots = chunk << 7;     // chunk * 128 float4 per row
    for (int v = t; v < nslots; v += 1024) {
      const int sl = v >> 7;
      const int fp = (v & 127) << 2;
      const float4 q = *(const float4*)&part[(size_t)id[s0 + sl] * M_DIM + fp];
      float4 f;
      f.x = fmaxf(q.x, 0.f);
      f.y = fmaxf(q.y, 0.f);
      f.z = fmaxf(q.z, 0.f);
      f.w = fmaxf(q.w, 0.f);
      *(float4*)&F[sl][fp] = f;
    }
    __syncthreads();
    for (int sl = 0; sl < chunk; ++sl) {
      const float4 a0 = *(const float4*)&F[sl][prow];          // bcast
      const float4 a1 = *(const float4*)&F[sl][prow + 4];      // bcast
      const float4 b0 = *(const float4*)&F[sl][tc * 4];        // contiguous
      const float4 b1 = *(const float4*)&F[sl][256 + tc * 4];  // contiguous
      const float av[8] = {a0.x, a0.y, a0.z, a0.w, a1.x, a1.y, a1.z, a1.w};
      const float bv[8] = {b0.x, b0.y, b0.z, b0.w, b1.x, b1.y, b1.z, b1.w};
#pragma unroll
      for (int r = 0; r < 8; ++r)
#pragma unroll
        for (int q = 0; q < 8; ++q)
          acc[r][q] += av[r] * bv[q];
    }
  }

  float* __restrict__ out = phi + (size_t)c * M_DIM * M_DIM;
#pragma unroll
  for (int r = 0; r < 8; ++r) {
    const size_t row = (size_t)(prow + r) * M_DIM;
    *(float4*)&out[row + tc * 4] =
        make_float4(acc[r][0], acc[r][1], acc[r][2], acc[r][3]);
    *(float4*)&out[row + 256 + tc * 4] =
        make_float4(acc[r][4], acc[r][5], acc[r][6], acc[r][7]);
  }
}

// ---------------------------------------------------------------------------
extern "C" void kernel_launch(void* const* d_in, const int* in_sizes, int n_in,
                              void* d_out, int out_size, void* d_ws,
                              size_t ws_size, hipStream_t stream) {
  const float* X      = (const float*)d_in[0];
  const float* W      = (const float*)d_in[1];
  const int*   labels = (const int*)d_in[2];

  float* out = (float*)d_out;
  float* phi = out;                                // C*M*M
  float* mu  = out + (size_t)C_N * M_DIM * M_DIM;  // C*M
  float* cnt = mu + (size_t)C_N * M_DIM;           // C

  float* part   = (float*)d_ws;                    // B*M fp32 = 2 MB (summed)
  int*   counts = (int*)((char*)d_ws + (size_t)B_N * M_DIM * sizeof(float));
  int*   idx    = counts + 128;                    // C*B ints

  hipMemsetAsync(part, 0, (size_t)B_N * M_DIM * sizeof(float), stream);
  hipLaunchKernelGGL(gemm_index_kernel, dim3(NGEMM + NIDX), dim3(256), 0,
                     stream, X, W, labels, part, counts, idx);
  hipLaunchKernelGGL(phi_mu_kernel, dim3(5, C_N), dim3(1024), 0, stream,
                     part, counts, idx, phi, mu, cnt);
}